// Round 5
// baseline (9159.772 us; speedup 1.0000x reference)
//
#include <hip/hip_runtime.h>
#include <cstddef>
#include <cstdint>

#define BATCH 256
#define SEQL  128
#define BL    (BATCH * SEQL)   // 32768 rows of x
#define DIM   512              // 448 + 32 + 32 (== UNITS)
#define N3    1536             // 3 * UNITS
#define NCLS  53

typedef float f32x4 __attribute__((ext_vector_type(4)));
typedef short s16x8 __attribute__((ext_vector_type(8)));
typedef short s16x4 __attribute__((ext_vector_type(4)));

__device__ __forceinline__ float bf2f(unsigned short u) {
    union { unsigned int i; float f; } v; v.i = ((unsigned int)u) << 16; return v.f;
}
__device__ __forceinline__ unsigned short f2bf(float f) {
    union { float f; unsigned int i; } v; v.f = f;
    unsigned int x = v.i;
    return (unsigned short)((x + 0x7fffu + ((x >> 16) & 1u)) >> 16);  // RNE
}
__device__ __forceinline__ float wave_sum(float v) {
    #pragma unroll
    for (int m = 32; m > 0; m >>= 1) v += __shfl_xor(v, m);
    return v;
}
__device__ __forceinline__ float wave_max(float v) {
    #pragma unroll
    for (int m = 32; m > 0; m >>= 1) v = fmaxf(v, __shfl_xor(v, m));
    return v;
}
__device__ __forceinline__ float sigmoidf(float x) { return 1.0f / (1.0f + expf(-x)); }

// ---------------------------------------------------------------------------
// Transpose + bf16-cast a [512,1536] fp32 weight into Wt[1536,512] bf16.
__global__ __launch_bounds__(256) void transpose_kernel(const float* __restrict__ W,
                                                        unsigned short* __restrict__ Wt) {
    __shared__ float tile[32][33];
    int tx = threadIdx.x & 31, ty = threadIdx.x >> 5;  // ty: 0..7
    int n0 = blockIdx.x * 32, k0 = blockIdx.y * 32;    // grid (48,16)
    #pragma unroll
    for (int r = 0; r < 4; ++r) {
        int kl = ty + r * 8;
        tile[kl][tx] = W[(size_t)(k0 + kl) * N3 + n0 + tx];
    }
    __syncthreads();
    #pragma unroll
    for (int r = 0; r < 4; ++r) {
        int nl = ty + r * 8;
        Wt[(size_t)(n0 + nl) * DIM + k0 + tx] = f2bf(tile[tx][nl]);
    }
}

// ---------------------------------------------------------------------------
// Gather word/pos embeddings -> X [32768, 512] bf16 (concat 448+32+32).
__global__ __launch_bounds__(64) void gather_kernel(const int* __restrict__ iw,
                                                    const int* __restrict__ ip1,
                                                    const int* __restrict__ ip2,
                                                    const float* __restrict__ wemb,
                                                    const float* __restrict__ pemb,
                                                    unsigned short* __restrict__ X) {
    int row = blockIdx.x;           // b*128 + l
    int tid = threadIdx.x;          // 64 threads x 8 elems
    int w = iw[row], p1 = ip1[row], p2 = ip2[row];
    int e0 = tid * 8;
    s16x8 o;
    #pragma unroll
    for (int j = 0; j < 8; ++j) {
        int e = e0 + j;
        float f;
        if (e < 448)      f = wemb[(size_t)w * 448 + e];
        else if (e < 480) f = pemb[p1 * 32 + (e - 448)];
        else              f = pemb[p2 * 32 + (e - 480)];
        o[j] = (short)f2bf(f);
    }
    *(s16x8*)(X + (size_t)row * DIM + e0) = o;
}

// ---------------------------------------------------------------------------
// XQ[dir] = X @ kernel[dir], stored FRAGMENT-MAJOR so the scan kernel reads
// fully-coalesced s16x4 chunks:
//   XQ[ ((tx*8 + bblk)*8 + w)*6144 + ((gate*4 + ni)*2 + mi)*256 + lane*4 + reg ]
//   == xp( b = bblk*32 + mi*16 + (lane>>4)*4 + reg,  l = tx,
//          n = gate*512 + w*64 + ni*16 + (lane&15) )
// Block: 256 thr / 4 waves. A-tile = 64 rows {(b0+i, l0+j): i<32, j<2}, m = j*32+i,
// staged in LDS (XOR swizzle). Wave wv owns m-tile wv; n-range = 384 (2 w x 3 gates).
// With this tiling the MFMA C-fragment maps to the XQ layout with addr
// base*256 + lane*4 + reg -> one s16x4 store per (gate, nii): fully coalesced.
__global__ __launch_bounds__(256, 2) void xq_gemm_kernel(const unsigned short* __restrict__ X,
                                                         const unsigned short* __restrict__ Ktf,
                                                         const unsigned short* __restrict__ Ktb,
                                                         unsigned short* __restrict__ XQf,
                                                         unsigned short* __restrict__ XQb) {
    int dir = blockIdx.z & 1;
    int ns  = blockIdx.z >> 1;           // 0..3 -> u0 = ns*128
    const unsigned short* Kt = dir ? Ktb : Ktf;
    unsigned short* XQ = dir ? XQb : XQf;
    int bblk = blockIdx.y;               // 0..7
    int b0 = bblk * 32;
    int l0 = blockIdx.x * 2;             // 0..126
    int u0 = ns * 128;

    __shared__ alignas(16) unsigned short As[64 * 512];   // 64 KB
    int tid = threadIdx.x;
    #pragma unroll
    for (int it = 0; it < 16; ++it) {
        int lin = (it * 256 + tid) * 16;      // byte offset into As (pre-swizzle)
        int row = lin >> 10;                  // 0..63, row = j*32 + i
        int off = lin & 1023;
        int i = row & 31, j = row >> 5;
        const char* src = (const char*)X + ((((size_t)(b0 + i)) * 128 + (size_t)(l0 + j)) << 10) + off;
        *(s16x8*)((char*)As + (lin ^ ((row & 7) << 4))) = *(const s16x8*)src;
    }
    __syncthreads();

    int lane = tid & 63, wv = tid >> 6;
    int lr = lane & 15, lg = lane >> 4;

    f32x4 acc[3][8];
    #pragma unroll
    for (int g = 0; g < 3; ++g)
        #pragma unroll
        for (int nii = 0; nii < 8; ++nii) acc[g][nii] = (f32x4){0.f, 0.f, 0.f, 0.f};

    int ar = wv * 16 + lr;
    for (int kk = 0; kk < 16; ++kk) {
        s16x8 a = *(const s16x8*)((const char*)As +
                    (((ar << 10) + (kk << 6) + (lg << 4)) ^ ((ar & 7) << 4)));
        #pragma unroll
        for (int g = 0; g < 3; ++g)
            #pragma unroll
            for (int nii = 0; nii < 8; ++nii) {
                const unsigned short* bp = Kt + ((size_t)(g * 512 + u0 + nii * 16 + lr) << 9)
                                              + (kk << 5) + (lg << 3);
                s16x8 b = *(const s16x8*)bp;
                acc[g][nii] = __builtin_amdgcn_mfma_f32_16x16x32_bf16(a, b, acc[g][nii], 0, 0, 0);
            }
    }

    int txo = l0 + (wv >> 1);
    int mi_t = wv & 1;
    #pragma unroll
    for (int g = 0; g < 3; ++g)
        #pragma unroll
        for (int nii = 0; nii < 8; ++nii) {
            int w_t  = ns * 2 + (nii >> 2);
            int ni_t = nii & 3;
            size_t base = (((size_t)txo * 8 + bblk) * 8 + w_t) * 6144
                        + (size_t)(((g * 4 + ni_t) * 2 + mi_t)) * 256;
            s16x4 o;
            #pragma unroll
            for (int reg = 0; reg < 4; ++reg) o[reg] = (short)f2bf(acc[g][nii][reg]);
            *(s16x4*)(XQ + base + lane * 4) = o;
        }
}

// ---------------------------------------------------------------------------
// Full 128-step GRU scan for all 4 runs in ONE kernel.
// Grid 32 WGs x 512 threads (8 waves). WG wg owns run (wg>>3), batch block
// (wg&7)*32 .. +32 (= state rows), ALL 512 u. H state: bf16 in LDS (double-
// buffered, XOR-swizzled), fp32 master in registers. Weights Bt streamed from
// L2 each step. Per step: pass1 (z,r gates) + pass2 (h gate) + elementwise.
// Run mapping (same as validated rounds 2/4):
//  run0 = GRU_f(x_f): xq slice t,     out slot t      -> HA
//  run1 = GRU_f(x_b): xq slice 127-t, out slot t      -> HB
//  run2 = GRU_b(x_b): xq slice 127-t, out slot 127-t  -> HC
//  run3 = GRU_b(x_f): xq slice t,     out slot 127-t  -> HD
// h(reference) = HA + HB + HC + HD (summed in the attention kernels).
__global__ __launch_bounds__(512, 2) void gru_scan_kernel(
    const unsigned short* __restrict__ XQf, const unsigned short* __restrict__ XQb,
    const unsigned short* __restrict__ Btf, const unsigned short* __restrict__ Btb,
    const float* __restrict__ gbf, const float* __restrict__ gbb,
    unsigned short* __restrict__ HA, unsigned short* __restrict__ HB,
    unsigned short* __restrict__ HC, unsigned short* __restrict__ HD) {
    int wg = blockIdx.x;
    int runidx = wg >> 3;
    int bblk = wg & 7;
    int b0 = bblk * 32;
    const unsigned short* Bt = (runidx < 2) ? Btf : Btb;
    const unsigned short* XQ = (runidx < 2) ? XQf : XQb;
    const float* gb = (runidx < 2) ? gbf : gbb;
    unsigned short* Hout = (runidx == 0) ? HA : (runidx == 1) ? HB : (runidx == 2) ? HC : HD;
    bool revx = (runidx == 1 || runidx == 2);
    bool revo = (runidx >= 2);

    int tid = threadIdx.x;
    int lane = tid & 63, w = tid >> 6;     // wave 0..7 -> u-slice w*64
    int lr = lane & 15, lg = lane >> 4;
    int u0 = w * 64;

    __shared__ alignas(16) unsigned short Hs[2][32 * 512];   // 2 x 32 KB

    {   // zero init buffer 0
        s16x8 z8 = (s16x8){0, 0, 0, 0, 0, 0, 0, 0};
        #pragma unroll
        for (int i = 0; i < 4; ++i) ((s16x8*)Hs[0])[tid + i * 512] = z8;
    }

    // biases (z/r: input+recurrent merged; h: kept separate for r*(ah+brh))
    float bZ[4], bR[4], bIH[4], bRH[4];
    #pragma unroll
    for (int ni = 0; ni < 4; ++ni) {
        int n = u0 + ni * 16 + lr;
        bZ[ni]  = gb[n] + gb[N3 + n];
        bR[ni]  = gb[512 + n] + gb[N3 + 512 + n];
        bIH[ni] = gb[1024 + n];
        bRH[ni] = gb[N3 + 1024 + n];
    }

    f32x4 hf[2][4];
    #pragma unroll
    for (int mi = 0; mi < 2; ++mi)
        #pragma unroll
        for (int ni = 0; ni < 4; ++ni) hf[mi][ni] = (f32x4){0.f, 0.f, 0.f, 0.f};

    __syncthreads();

    for (int t = 0; t < SEQL; ++t) {
        int cur = t & 1;
        int tx = revx ? (127 - t) : t;
        int th = revo ? (127 - t) : t;

        // x-projection fragments: 24 coalesced 8-byte loads
        const unsigned short* xqb = XQ + (((size_t)tx * 8 + bblk) * 8 + w) * 6144 + (size_t)lane * 4;
        s16x4 xq[3][4][2];
        #pragma unroll
        for (int g = 0; g < 3; ++g)
            #pragma unroll
            for (int ni = 0; ni < 4; ++ni)
                #pragma unroll
                for (int mi = 0; mi < 2; ++mi)
                    xq[g][ni][mi] = *(const s16x4*)(xqb + ((g * 4 + ni) * 2 + mi) * 256);

        const char* hs = (const char*)Hs[cur];
        int r0 = lr, r1 = 16 + lr;

        // ---- pass 1: z and r gate GEMMs ----
        f32x4 aZ[2][4], aR[2][4];
        #pragma unroll
        for (int mi = 0; mi < 2; ++mi)
            #pragma unroll
            for (int ni = 0; ni < 4; ++ni) {
                aZ[mi][ni] = (f32x4){0.f, 0.f, 0.f, 0.f};
                aR[mi][ni] = (f32x4){0.f, 0.f, 0.f, 0.f};
            }
        for (int kk = 0; kk < 16; ++kk) {
            s16x8 a0 = *(const s16x8*)(hs + (((r0 << 10) + (kk << 6) + (lg << 4)) ^ ((r0 & 7) << 4)));
            s16x8 a1 = *(const s16x8*)(hs + (((r1 << 10) + (kk << 6) + (lg << 4)) ^ ((r1 & 7) << 4)));
            #pragma unroll
            for (int ni = 0; ni < 4; ++ni) {
                const unsigned short* bp = Bt + ((size_t)(u0 + ni * 16 + lr) << 9) + (kk << 5) + (lg << 3);
                s16x8 bz = *(const s16x8*)bp;
                s16x8 br = *(const s16x8*)(bp + (512 << 9));
                aZ[0][ni] = __builtin_amdgcn_mfma_f32_16x16x32_bf16(a0, bz, aZ[0][ni], 0, 0, 0);
                aZ[1][ni] = __builtin_amdgcn_mfma_f32_16x16x32_bf16(a1, bz, aZ[1][ni], 0, 0, 0);
                aR[0][ni] = __builtin_amdgcn_mfma_f32_16x16x32_bf16(a0, br, aR[0][ni], 0, 0, 0);
                aR[1][ni] = __builtin_amdgcn_mfma_f32_16x16x32_bf16(a1, br, aR[1][ni], 0, 0, 0);
            }
        }
        // finish z, r in place (aZ := z, aR := r)
        #pragma unroll
        for (int mi = 0; mi < 2; ++mi)
            #pragma unroll
            for (int ni = 0; ni < 4; ++ni)
                #pragma unroll
                for (int reg = 0; reg < 4; ++reg) {
                    aZ[mi][ni][reg] = sigmoidf(bf2f((unsigned short)xq[0][ni][mi][reg]) + aZ[mi][ni][reg] + bZ[ni]);
                    aR[mi][ni][reg] = sigmoidf(bf2f((unsigned short)xq[1][ni][mi][reg]) + aR[mi][ni][reg] + bR[ni]);
                }

        // ---- pass 2: h gate GEMM ----
        f32x4 aH[2][4];
        #pragma unroll
        for (int mi = 0; mi < 2; ++mi)
            #pragma unroll
            for (int ni = 0; ni < 4; ++ni) aH[mi][ni] = (f32x4){0.f, 0.f, 0.f, 0.f};
        for (int kk = 0; kk < 16; ++kk) {
            s16x8 a0 = *(const s16x8*)(hs + (((r0 << 10) + (kk << 6) + (lg << 4)) ^ ((r0 & 7) << 4)));
            s16x8 a1 = *(const s16x8*)(hs + (((r1 << 10) + (kk << 6) + (lg << 4)) ^ ((r1 & 7) << 4)));
            #pragma unroll
            for (int ni = 0; ni < 4; ++ni) {
                const unsigned short* bp = Bt + ((size_t)(u0 + ni * 16 + lr) << 9) + (kk << 5) + (lg << 3)
                                              + ((size_t)1024 << 9);
                s16x8 bh = *(const s16x8*)bp;
                aH[0][ni] = __builtin_amdgcn_mfma_f32_16x16x32_bf16(a0, bh, aH[0][ni], 0, 0, 0);
                aH[1][ni] = __builtin_amdgcn_mfma_f32_16x16x32_bf16(a1, bh, aH[1][ni], 0, 0, 0);
            }
        }

        // ---- finish: gate math, state update, writes ----
        char* hn_lds = (char*)Hs[cur ^ 1];
        #pragma unroll
        for (int mi = 0; mi < 2; ++mi)
            #pragma unroll
            for (int ni = 0; ni < 4; ++ni)
                #pragma unroll
                for (int reg = 0; reg < 4; ++reg) {
                    int row = mi * 16 + lg * 4 + reg;
                    int u = u0 + ni * 16 + lr;
                    float hh = tanhf(bf2f((unsigned short)xq[2][ni][mi][reg]) + bIH[ni]
                                     + aR[mi][ni][reg] * (aH[mi][ni][reg] + bRH[ni]));
                    float z = aZ[mi][ni][reg];
                    float hnv = z * hf[mi][ni][reg] + (1.0f - z) * hh;
                    hf[mi][ni][reg] = hnv;
                    unsigned short hb = f2bf(hnv);
                    *(unsigned short*)(hn_lds + (((row << 10) + (u << 1)) ^ ((row & 7) << 4))) = hb;
                    Hout[((size_t)(b0 + row) * SEQL + th) * DIM + u] = hb;
                }
        __syncthreads();
    }
}

// ---------------------------------------------------------------------------
// scores[b,l] = sum_u tanh(h[b,l,u]) * attw[u],  h = HA+HB+HC+HD
__global__ __launch_bounds__(64) void attn_scores_kernel(const unsigned short* __restrict__ HA,
                                                         const unsigned short* __restrict__ HB,
                                                         const unsigned short* __restrict__ HC,
                                                         const unsigned short* __restrict__ HD,
                                                         const float* __restrict__ attw,
                                                         float* __restrict__ scores) {
    int bl = blockIdx.x;   // grid 32768
    int lane = threadIdx.x;
    size_t base = (size_t)bl * DIM + lane * 8;
    s16x8 h1 = *(const s16x8*)(HA + base);
    s16x8 h2 = *(const s16x8*)(HB + base);
    s16x8 h3 = *(const s16x8*)(HC + base);
    s16x8 h4 = *(const s16x8*)(HD + base);
    float s = 0.0f;
    #pragma unroll
    for (int j = 0; j < 8; ++j) {
        float hv = bf2f((unsigned short)h1[j]) + bf2f((unsigned short)h2[j])
                 + bf2f((unsigned short)h3[j]) + bf2f((unsigned short)h4[j]);
        s += tanhf(hv) * attw[lane * 8 + j];
    }
    s = wave_sum(s);
    if (lane == 0) scores[bl] = s;
}

// alpha[b,:] = softmax over L=128
__global__ __launch_bounds__(64) void softmax_l_kernel(const float* __restrict__ scores,
                                                       float* __restrict__ alpha) {
    int b = blockIdx.x, lane = threadIdx.x;
    float s0 = scores[b * SEQL + lane];
    float s1 = scores[b * SEQL + 64 + lane];
    float m = wave_max(fmaxf(s0, s1));
    float e0 = expf(s0 - m), e1 = expf(s1 - m);
    float sum = wave_sum(e0 + e1);
    alpha[b * SEQL + lane] = e0 / sum;
    alpha[b * SEQL + 64 + lane] = e1 / sum;
}

// w_att_r[b,u] = sum_l alpha*h ; r = tanh(w); e[b] = sum_u r*sen_a*sen_r
__global__ __launch_bounds__(256) void attn_apply_kernel(const unsigned short* __restrict__ HA,
                                                         const unsigned short* __restrict__ HB,
                                                         const unsigned short* __restrict__ HC,
                                                         const unsigned short* __restrict__ HD,
                                                         const float* __restrict__ alpha,
                                                         const float* __restrict__ sena,
                                                         const float* __restrict__ senr,
                                                         float* __restrict__ rbuf,
                                                         float* __restrict__ ebuf) {
    int b = blockIdx.x, tid = threadIdx.x;
    __shared__ float al[SEQL];
    __shared__ float red[4];
    if (tid < SEQL) al[tid] = alpha[b * SEQL + tid];
    __syncthreads();
    float w0 = 0.0f, w1 = 0.0f;
    for (int l = 0; l < SEQL; ++l) {
        size_t base = ((size_t)b * SEQL + l) * DIM;
        float a = al[l];
        w0 += a * (bf2f(HA[base + tid]) + bf2f(HB[base + tid])
                 + bf2f(HC[base + tid]) + bf2f(HD[base + tid]));
        w1 += a * (bf2f(HA[base + 256 + tid]) + bf2f(HB[base + 256 + tid])
                 + bf2f(HC[base + 256 + tid]) + bf2f(HD[base + 256 + tid]));
    }
    float r0 = tanhf(w0), r1 = tanhf(w1);
    rbuf[(size_t)b * DIM + tid] = r0;
    rbuf[(size_t)b * DIM + 256 + tid] = r1;
    float p = r0 * sena[tid] * senr[tid] + r1 * sena[256 + tid] * senr[256 + tid];
    p = wave_sum(p);
    int wid = tid >> 6;
    if ((tid & 63) == 0) red[wid] = p;
    __syncthreads();
    if (tid == 0) ebuf[b] = red[0] + red[1] + red[2] + red[3];
}

// a = softmax over batch (256)
__global__ __launch_bounds__(64) void batch_softmax_kernel(const float* __restrict__ ebuf,
                                                           float* __restrict__ abuf) {
    int lane = threadIdx.x;
    float v0 = ebuf[lane], v1 = ebuf[64 + lane], v2 = ebuf[128 + lane], v3 = ebuf[192 + lane];
    float m = wave_max(fmaxf(fmaxf(v0, v1), fmaxf(v2, v3)));
    float e0 = expf(v0 - m), e1 = expf(v1 - m), e2 = expf(v2 - m), e3 = expf(v3 - m);
    float s = wave_sum(e0 + e1 + e2 + e3);
    abuf[lane] = e0 / s; abuf[64 + lane] = e1 / s;
    abuf[128 + lane] = e2 / s; abuf[192 + lane] = e3 / s;
}

// logits[b,c] = a[b]*(r[b]·sen_s[c]) + sen_d[c]; out = softmax over c
__global__ __launch_bounds__(64) void final_out_kernel(const float* __restrict__ rbuf,
                                                       const float* __restrict__ abuf,
                                                       const float* __restrict__ sens,
                                                       const float* __restrict__ send,
                                                       float* __restrict__ out) {
    int b = blockIdx.x, lane = threadIdx.x;
    __shared__ float lg[NCLS];
    float ab = abuf[b];
    float rv[8];
    #pragma unroll
    for (int j = 0; j < 8; ++j) rv[j] = rbuf[(size_t)b * DIM + j * 64 + lane];
    for (int c = 0; c < NCLS; ++c) {
        float d = 0.0f;
        #pragma unroll
        for (int j = 0; j < 8; ++j) d += rv[j] * sens[(size_t)c * DIM + j * 64 + lane];
        d = wave_sum(d);
        if (lane == 0) lg[c] = ab * d + send[c];
    }
    __syncthreads();
    float x = (lane < NCLS) ? lg[lane] : -3.0e38f;
    float m = wave_max(x);
    float ex = (lane < NCLS) ? expf(x - m) : 0.0f;
    float s = wave_sum(ex);
    if (lane < NCLS) out[b * NCLS + lane] = ex / s;
}

// ---------------------------------------------------------------------------
extern "C" void kernel_launch(void* const* d_in, const int* in_sizes, int n_in,
                              void* d_out, int out_size, void* d_ws, size_t ws_size,
                              hipStream_t stream) {
    (void)in_sizes; (void)n_in; (void)out_size; (void)ws_size;
    const int*   iw   = (const int*)d_in[0];
    const int*   ip1  = (const int*)d_in[1];
    const int*   ip2  = (const int*)d_in[2];
    const float* wemb = (const float*)d_in[3];
    const float* pemb = (const float*)d_in[4];
    const float* kf   = (const float*)d_in[5];
    const float* rf   = (const float*)d_in[6];
    const float* gbf  = (const float*)d_in[7];
    const float* kb   = (const float*)d_in[8];
    const float* rb   = (const float*)d_in[9];
    const float* gbb  = (const float*)d_in[10];
    const float* attw = (const float*)d_in[11];
    const float* sena = (const float*)d_in[12];
    const float* senr = (const float*)d_in[13];
    const float* send = (const float*)d_in[14];
    const float* sens = (const float*)d_in[15];
    float* out = (float*)d_out;

    char* p = (char*)d_ws;
    auto take = [&](size_t n) { char* q = p; p += ((n + 255) & ~(size_t)255); return q; };
    // X is dead after xq_gemm; HA aliases it (scan fully overwrites).
    unsigned short* X    = (unsigned short*)take((size_t)BL * DIM * 2);       // 33.5 MB (= HA)
    unsigned short* Ktf  = (unsigned short*)take((size_t)N3 * DIM * 2);
    unsigned short* Ktb  = (unsigned short*)take((size_t)N3 * DIM * 2);
    unsigned short* Btf  = (unsigned short*)take((size_t)N3 * DIM * 2);
    unsigned short* Btb  = (unsigned short*)take((size_t)N3 * DIM * 2);
    unsigned short* XQf  = (unsigned short*)take((size_t)BL * N3 * 2);        // 100.7 MB
    unsigned short* XQb  = (unsigned short*)take((size_t)BL * N3 * 2);        // 100.7 MB
    unsigned short* HB   = (unsigned short*)take((size_t)BL * DIM * 2);       // 33.5 MB
    unsigned short* HC   = (unsigned short*)take((size_t)BL * DIM * 2);       // 33.5 MB
    unsigned short* HD   = (unsigned short*)take((size_t)BL * DIM * 2);       // 33.5 MB
    float* scores = (float*)take((size_t)BL * 4);
    float* alpha  = (float*)take((size_t)BL * 4);
    float* rbuf   = (float*)take((size_t)BATCH * DIM * 4);
    float* ebuf   = (float*)take((size_t)BATCH * 4);
    float* abuf   = (float*)take((size_t)BATCH * 4);
    unsigned short* HA = X;   // alias

    transpose_kernel<<<dim3(48, 16), 256, 0, stream>>>(kf, Ktf);
    transpose_kernel<<<dim3(48, 16), 256, 0, stream>>>(kb, Ktb);
    transpose_kernel<<<dim3(48, 16), 256, 0, stream>>>(rf, Btf);
    transpose_kernel<<<dim3(48, 16), 256, 0, stream>>>(rb, Btb);
    gather_kernel<<<BL, 64, 0, stream>>>(iw, ip1, ip2, wemb, pemb, X);

    xq_gemm_kernel<<<dim3(64, 8, 8), 256, 0, stream>>>(X, Ktf, Ktb, XQf, XQb);

    gru_scan_kernel<<<32, 512, 0, stream>>>(XQf, XQb, Btf, Btb, gbf, gbb, HA, HB, HC, HD);

    attn_scores_kernel<<<BL, 64, 0, stream>>>(HA, HB, HC, HD, attw, scores);
    softmax_l_kernel<<<BATCH, 64, 0, stream>>>(scores, alpha);
    attn_apply_kernel<<<BATCH, 256, 0, stream>>>(HA, HB, HC, HD, alpha, sena, senr, rbuf, ebuf);
    batch_softmax_kernel<<<1, 64, 0, stream>>>(ebuf, abuf);
    final_out_kernel<<<BATCH, 64, 0, stream>>>(rbuf, abuf, sens, send, out);
}

// Round 6
// 5620.109 us; speedup vs baseline: 1.6298x; 1.6298x over previous
//
#include <hip/hip_runtime.h>
#include <hip/hip_cooperative_groups.h>
#include <cstddef>
#include <cstdint>

namespace cg = cooperative_groups;

#define BATCH 256
#define SEQL  128
#define BL    (BATCH * SEQL)   // 32768 rows of x
#define DIM   512              // 448 + 32 + 32 (== UNITS)
#define N3    1536             // 3 * UNITS
#define NCLS  53
#define HGN   (4 * 256 * 512)  // one H ping-pong buffer (elems)

typedef float f32x4 __attribute__((ext_vector_type(4)));
typedef short s16x8 __attribute__((ext_vector_type(8)));
typedef short s16x4 __attribute__((ext_vector_type(4)));

__device__ __forceinline__ float bf2f(unsigned short u) {
    union { unsigned int i; float f; } v; v.i = ((unsigned int)u) << 16; return v.f;
}
__device__ __forceinline__ unsigned short f2bf(float f) {
    union { float f; unsigned int i; } v; v.f = f;
    unsigned int x = v.i;
    return (unsigned short)((x + 0x7fffu + ((x >> 16) & 1u)) >> 16);  // RNE
}
__device__ __forceinline__ float wave_sum(float v) {
    #pragma unroll
    for (int m = 32; m > 0; m >>= 1) v += __shfl_xor(v, m);
    return v;
}
__device__ __forceinline__ float wave_max(float v) {
    #pragma unroll
    for (int m = 32; m > 0; m >>= 1) v = fmaxf(v, __shfl_xor(v, m));
    return v;
}
__device__ __forceinline__ float sigmoidf(float x) { return 1.0f / (1.0f + expf(-x)); }

// ---------------------------------------------------------------------------
// Transpose + bf16-cast a [512,1536] fp32 weight into Wt[1536,512] bf16.
__global__ __launch_bounds__(256) void transpose_kernel(const float* __restrict__ W,
                                                        unsigned short* __restrict__ Wt) {
    __shared__ float tile[32][33];
    int tx = threadIdx.x & 31, ty = threadIdx.x >> 5;  // ty: 0..7
    int n0 = blockIdx.x * 32, k0 = blockIdx.y * 32;    // grid (48,16)
    #pragma unroll
    for (int r = 0; r < 4; ++r) {
        int kl = ty + r * 8;
        tile[kl][tx] = W[(size_t)(k0 + kl) * N3 + n0 + tx];
    }
    __syncthreads();
    #pragma unroll
    for (int r = 0; r < 4; ++r) {
        int nl = ty + r * 8;
        Wt[(size_t)(n0 + nl) * DIM + k0 + tx] = f2bf(tile[tx][nl]);
    }
}

// ---------------------------------------------------------------------------
// Gather word/pos embeddings -> X [32768, 512] bf16 (concat 448+32+32).
__global__ __launch_bounds__(64) void gather_kernel(const int* __restrict__ iw,
                                                    const int* __restrict__ ip1,
                                                    const int* __restrict__ ip2,
                                                    const float* __restrict__ wemb,
                                                    const float* __restrict__ pemb,
                                                    unsigned short* __restrict__ X) {
    int row = blockIdx.x;           // b*128 + l
    int tid = threadIdx.x;          // 64 threads x 8 elems
    int w = iw[row], p1 = ip1[row], p2 = ip2[row];
    int e0 = tid * 8;
    s16x8 o;
    #pragma unroll
    for (int j = 0; j < 8; ++j) {
        int e = e0 + j;
        float f;
        if (e < 448)      f = wemb[(size_t)w * 448 + e];
        else if (e < 480) f = pemb[p1 * 32 + (e - 448)];
        else              f = pemb[p2 * 32 + (e - 480)];
        o[j] = (short)f2bf(f);
    }
    *(s16x8*)(X + (size_t)row * DIM + e0) = o;
}

// ---------------------------------------------------------------------------
// XQ[dir] = X @ kernel[dir], FRAGMENT-MAJOR layout (validated round 5):
// element (b, l, n = g*512+u) at
//   ((l*8 + (b>>5))*8 + (u>>6))*6144 + ((g*4 + ((u>>4)&3))*2 + ((b>>4)&1))*256
//   + ((u&15) | (((b>>2)&3)<<4))*4 + (b&3)
// v2: 32-row A-tile (32 KB LDS) -> 4+ blocks/CU. Block: (l, bblk, dir/ns).
// 4 waves: mi = wv>>1 (m-tile), wc = wv&1 (u-half of 64). 12 accs/wave.
__global__ __launch_bounds__(256, 4) void xq_gemm_kernel(const unsigned short* __restrict__ X,
                                                         const unsigned short* __restrict__ Ktf,
                                                         const unsigned short* __restrict__ Ktb,
                                                         unsigned short* __restrict__ XQf,
                                                         unsigned short* __restrict__ XQb) {
    int dir = blockIdx.z & 1;
    int ns  = blockIdx.z >> 1;           // 0..3 -> u0 = ns*128
    const unsigned short* Kt = dir ? Ktb : Ktf;
    unsigned short* XQ = dir ? XQb : XQf;
    int l    = blockIdx.x;               // 0..127
    int bblk = blockIdx.y;               // 0..7
    int b0 = bblk * 32;
    int u0 = ns * 128;

    __shared__ alignas(16) unsigned short As[32 * 512];   // 32 KB
    int tid = threadIdx.x;
    #pragma unroll
    for (int it = 0; it < 8; ++it) {
        int lin = (it * 256 + tid) * 16;      // byte offset (pre-swizzle)
        int row = lin >> 10;                  // 0..31
        int off = lin & 1023;
        const char* src = (const char*)X + ((((size_t)(b0 + row)) * 128 + l) << 10) + off;
        *(s16x8*)((char*)As + (lin ^ ((row & 7) << 4))) = *(const s16x8*)src;
    }
    __syncthreads();

    int lane = tid & 63, wv = tid >> 6;
    int mi = wv >> 1, wc = wv & 1;
    int lr = lane & 15, lg = lane >> 4;

    f32x4 acc[3][4];
    #pragma unroll
    for (int g = 0; g < 3; ++g)
        #pragma unroll
        for (int ni = 0; ni < 4; ++ni) acc[g][ni] = (f32x4){0.f, 0.f, 0.f, 0.f};

    int ar = mi * 16 + lr;
    #pragma unroll 4
    for (int kk = 0; kk < 16; ++kk) {
        s16x8 a = *(const s16x8*)((const char*)As +
                    (((ar << 10) + (kk << 6) + (lg << 4)) ^ ((ar & 7) << 4)));
        #pragma unroll
        for (int g = 0; g < 3; ++g)
            #pragma unroll
            for (int ni = 0; ni < 4; ++ni) {
                int brow = g * 512 + u0 + wc * 64 + ni * 16 + lr;
                s16x8 b = *(const s16x8*)(Kt + ((size_t)brow << 9) + (kk << 5) + (lg << 3));
                acc[g][ni] = __builtin_amdgcn_mfma_f32_16x16x32_bf16(a, b, acc[g][ni], 0, 0, 0);
            }
    }

    int w_t = ns * 2 + wc;
    #pragma unroll
    for (int g = 0; g < 3; ++g)
        #pragma unroll
        for (int ni = 0; ni < 4; ++ni) {
            size_t base = (((size_t)l * 8 + bblk) * 8 + w_t) * 6144
                        + (size_t)((g * 4 + ni) * 2 + mi) * 256;
            s16x4 o;
            #pragma unroll
            for (int reg = 0; reg < 4; ++reg) o[reg] = (short)f2bf(acc[g][ni][reg]);
            *(s16x4*)(XQ + base + lane * 4) = o;
        }
}

// ---------------------------------------------------------------------------
// Cooperative persistent GRU scan: 256 WGs x 512 thr, one grid.sync per step.
// WG = (run = wg&3, uslc = (wg>>2)&31, rowh = wg>>7).
// Owns: weight slice (3 gates x 16 u x 512 K, 48 KB) LDS-resident;
//       output H[rows rowh*128..+128, u-slice 16]; fp32 master in registers.
// Per step: A (prev H, bf16) read from global ping-pong; 48 MFMA/wave; gate
// math; write next-H (global) + Hout time-slot. grid.sync().
// Runs: 0=GRU_f(x_f)->HA slot t; 1=GRU_f(x_b)->HB slot t;
//       2=GRU_b(x_b)->HC slot 127-t; 3=GRU_b(x_f)->HD slot 127-t.
__global__ __launch_bounds__(512, 2) void gru_coop_kernel(
    const unsigned short* __restrict__ XQf, const unsigned short* __restrict__ XQb,
    const unsigned short* __restrict__ Btf, const unsigned short* __restrict__ Btb,
    const float* __restrict__ gbf, const float* __restrict__ gbb,
    unsigned short* __restrict__ Hg,
    unsigned short* __restrict__ HA, unsigned short* __restrict__ HB,
    unsigned short* __restrict__ HC, unsigned short* __restrict__ HD) {
    cg::grid_group grid = cg::this_grid();
    int wg = blockIdx.x;                 // 0..255
    int run  = wg & 3;
    int uslc = (wg >> 2) & 31;
    int rowh = wg >> 7;                  // 0..1
    const unsigned short* Bt = (run < 2) ? Btf : Btb;
    const unsigned short* XQ = (run < 2) ? XQf : XQb;
    const float* gb = (run < 2) ? gbf : gbb;
    unsigned short* Hout = (run == 0) ? HA : (run == 1) ? HB : (run == 2) ? HC : HD;
    bool revx = (run == 1 || run == 2);
    bool revo = (run >= 2);

    int tid = threadIdx.x;
    int lane = tid & 63, wv = tid >> 6;  // wv 0..7 -> m-tile rowh*128 + wv*16
    int lr = lane & 15, lg = lane >> 4;

    // ---- weight slice -> LDS (48 rows x 512, XOR-swizzled) ----
    __shared__ alignas(16) unsigned short Ws[48 * 512];   // 48 KB
    #pragma unroll
    for (int it = 0; it < 6; ++it) {
        int lin = (it * 512 + tid) * 16;   // byte
        int wrow = lin >> 10;              // 0..47 = g*16 + i
        int off = lin & 1023;
        int g = wrow >> 4, i = wrow & 15;
        const char* src = (const char*)Bt + (((size_t)(g * 512 + uslc * 16 + i)) << 10) + off;
        *(s16x8*)((char*)Ws + (lin ^ ((wrow & 7) << 4))) = *(const s16x8*)src;
    }

    int u_col = uslc * 16 + lr;
    float bZv  = gb[u_col] + gb[N3 + u_col];
    float bRv  = gb[512 + u_col] + gb[N3 + 512 + u_col];
    float bIHv = gb[1024 + u_col];
    float bRHv = gb[N3 + 1024 + u_col];

    int mrow0 = rowh * 128 + wv * 16;    // m-tile base row (batch index)
    int arow  = mrow0 + lr;              // A-fragment row
    int bblk = rowh * 4 + (wv >> 1);
    int mi = wv & 1;
    int w_t = uslc >> 2, ni_t = uslc & 3;

    // zero initial state (own elements of Hg buffer 0) + register master
    f32x4 hm = (f32x4){0.f, 0.f, 0.f, 0.f};
    #pragma unroll
    for (int reg = 0; reg < 4; ++reg) {
        int row = mrow0 + lg * 4 + reg;
        Hg[((size_t)(run * 256 + row) << 9) + u_col] = 0;
    }
    __syncthreads();
    grid.sync();

    for (int t = 0; t < SEQL; ++t) {
        const unsigned short* cur = Hg + (size_t)(t & 1) * HGN;
        unsigned short* nxt = Hg + (size_t)((t + 1) & 1) * HGN;
        int tx = revx ? (127 - t) : t;
        int th = revo ? (127 - t) : t;

        // x-projection fragments (3 coalesced 8-B loads)
        const unsigned short* xqb = XQ + (((size_t)tx * 8 + bblk) * 8 + w_t) * 6144
                                       + (size_t)lane * 4;
        s16x4 xqz = *(const s16x4*)(xqb + ((0 * 4 + ni_t) * 2 + mi) * 256);
        s16x4 xqr = *(const s16x4*)(xqb + ((1 * 4 + ni_t) * 2 + mi) * 256);
        s16x4 xqh = *(const s16x4*)(xqb + ((2 * 4 + ni_t) * 2 + mi) * 256);

        const unsigned short* ap = cur + ((size_t)(run * 256 + arow) << 9) + (lg << 3);

        f32x4 aZ = (f32x4){0.f, 0.f, 0.f, 0.f};
        f32x4 aR = (f32x4){0.f, 0.f, 0.f, 0.f};
        f32x4 aH = (f32x4){0.f, 0.f, 0.f, 0.f};
        const char* wsb = (const char*)Ws;
        #pragma unroll 8
        for (int kk = 0; kk < 16; ++kk) {
            s16x8 a = *(const s16x8*)(ap + (kk << 5));
            int sw = (lr & 7) << 4;
            s16x8 bz = *(const s16x8*)(wsb + ((((0 * 16 + lr) << 10) + (kk << 6) + (lg << 4)) ^ sw));
            s16x8 br = *(const s16x8*)(wsb + ((((1 * 16 + lr) << 10) + (kk << 6) + (lg << 4)) ^ sw));
            s16x8 bh = *(const s16x8*)(wsb + ((((2 * 16 + lr) << 10) + (kk << 6) + (lg << 4)) ^ sw));
            aZ = __builtin_amdgcn_mfma_f32_16x16x32_bf16(a, bz, aZ, 0, 0, 0);
            aR = __builtin_amdgcn_mfma_f32_16x16x32_bf16(a, br, aR, 0, 0, 0);
            aH = __builtin_amdgcn_mfma_f32_16x16x32_bf16(a, bh, aH, 0, 0, 0);
        }

        #pragma unroll
        for (int reg = 0; reg < 4; ++reg) {
            int row = mrow0 + lg * 4 + reg;
            float z  = sigmoidf(bf2f((unsigned short)xqz[reg]) + bZv + aZ[reg]);
            float rg = sigmoidf(bf2f((unsigned short)xqr[reg]) + bRv + aR[reg]);
            float hh = tanhf(bf2f((unsigned short)xqh[reg]) + bIHv + rg * (aH[reg] + bRHv));
            float hn = z * hm[reg] + (1.0f - z) * hh;
            hm[reg] = hn;
            unsigned short hb = f2bf(hn);
            nxt[((size_t)(run * 256 + row) << 9) + u_col] = hb;
            Hout[(((size_t)row * SEQL) + th) * DIM + u_col] = hb;
        }
        grid.sync();
    }
}

// ---------------------------------------------------------------------------
// scores[b,l] = sum_u tanh(h[b,l,u]) * attw[u],  h = HA+HB+HC+HD
__global__ __launch_bounds__(64) void attn_scores_kernel(const unsigned short* __restrict__ HA,
                                                         const unsigned short* __restrict__ HB,
                                                         const unsigned short* __restrict__ HC,
                                                         const unsigned short* __restrict__ HD,
                                                         const float* __restrict__ attw,
                                                         float* __restrict__ scores) {
    int bl = blockIdx.x;   // grid 32768
    int lane = threadIdx.x;
    size_t base = (size_t)bl * DIM + lane * 8;
    s16x8 h1 = *(const s16x8*)(HA + base);
    s16x8 h2 = *(const s16x8*)(HB + base);
    s16x8 h3 = *(const s16x8*)(HC + base);
    s16x8 h4 = *(const s16x8*)(HD + base);
    float s = 0.0f;
    #pragma unroll
    for (int j = 0; j < 8; ++j) {
        float hv = bf2f((unsigned short)h1[j]) + bf2f((unsigned short)h2[j])
                 + bf2f((unsigned short)h3[j]) + bf2f((unsigned short)h4[j]);
        s += tanhf(hv) * attw[lane * 8 + j];
    }
    s = wave_sum(s);
    if (lane == 0) scores[bl] = s;
}

// alpha[b,:] = softmax over L=128
__global__ __launch_bounds__(64) void softmax_l_kernel(const float* __restrict__ scores,
                                                       float* __restrict__ alpha) {
    int b = blockIdx.x, lane = threadIdx.x;
    float s0 = scores[b * SEQL + lane];
    float s1 = scores[b * SEQL + 64 + lane];
    float m = wave_max(fmaxf(s0, s1));
    float e0 = expf(s0 - m), e1 = expf(s1 - m);
    float sum = wave_sum(e0 + e1);
    alpha[b * SEQL + lane] = e0 / sum;
    alpha[b * SEQL + 64 + lane] = e1 / sum;
}

// w_att_r[b,u] = sum_l alpha*h ; r = tanh(w); e[b] = sum_u r*sen_a*sen_r
__global__ __launch_bounds__(256) void attn_apply_kernel(const unsigned short* __restrict__ HA,
                                                         const unsigned short* __restrict__ HB,
                                                         const unsigned short* __restrict__ HC,
                                                         const unsigned short* __restrict__ HD,
                                                         const float* __restrict__ alpha,
                                                         const float* __restrict__ sena,
                                                         const float* __restrict__ senr,
                                                         float* __restrict__ rbuf,
                                                         float* __restrict__ ebuf) {
    int b = blockIdx.x, tid = threadIdx.x;
    __shared__ float al[SEQL];
    __shared__ float red[4];
    if (tid < SEQL) al[tid] = alpha[b * SEQL + tid];
    __syncthreads();
    float w0 = 0.0f, w1 = 0.0f;
    for (int l = 0; l < SEQL; ++l) {
        size_t base = ((size_t)b * SEQL + l) * DIM;
        float a = al[l];
        w0 += a * (bf2f(HA[base + tid]) + bf2f(HB[base + tid])
                 + bf2f(HC[base + tid]) + bf2f(HD[base + tid]));
        w1 += a * (bf2f(HA[base + 256 + tid]) + bf2f(HB[base + 256 + tid])
                 + bf2f(HC[base + 256 + tid]) + bf2f(HD[base + 256 + tid]));
    }
    float r0 = tanhf(w0), r1 = tanhf(w1);
    rbuf[(size_t)b * DIM + tid] = r0;
    rbuf[(size_t)b * DIM + 256 + tid] = r1;
    float p = r0 * sena[tid] * senr[tid] + r1 * sena[256 + tid] * senr[256 + tid];
    p = wave_sum(p);
    int wid = tid >> 6;
    if ((tid & 63) == 0) red[wid] = p;
    __syncthreads();
    if (tid == 0) ebuf[b] = red[0] + red[1] + red[2] + red[3];
}

// a = softmax over batch (256)
__global__ __launch_bounds__(64) void batch_softmax_kernel(const float* __restrict__ ebuf,
                                                           float* __restrict__ abuf) {
    int lane = threadIdx.x;
    float v0 = ebuf[lane], v1 = ebuf[64 + lane], v2 = ebuf[128 + lane], v3 = ebuf[192 + lane];
    float m = wave_max(fmaxf(fmaxf(v0, v1), fmaxf(v2, v3)));
    float e0 = expf(v0 - m), e1 = expf(v1 - m), e2 = expf(v2 - m), e3 = expf(v3 - m);
    float s = wave_sum(e0 + e1 + e2 + e3);
    abuf[lane] = e0 / s; abuf[64 + lane] = e1 / s;
    abuf[128 + lane] = e2 / s; abuf[192 + lane] = e3 / s;
}

// logits[b,c] = a[b]*(r[b]·sen_s[c]) + sen_d[c]; out = softmax over c
__global__ __launch_bounds__(64) void final_out_kernel(const float* __restrict__ rbuf,
                                                       const float* __restrict__ abuf,
                                                       const float* __restrict__ sens,
                                                       const float* __restrict__ send,
                                                       float* __restrict__ out) {
    int b = blockIdx.x, lane = threadIdx.x;
    __shared__ float lg[NCLS];
    float ab = abuf[b];
    float rv[8];
    #pragma unroll
    for (int j = 0; j < 8; ++j) rv[j] = rbuf[(size_t)b * DIM + j * 64 + lane];
    for (int c = 0; c < NCLS; ++c) {
        float d = 0.0f;
        #pragma unroll
        for (int j = 0; j < 8; ++j) d += rv[j] * sens[(size_t)c * DIM + j * 64 + lane];
        d = wave_sum(d);
        if (lane == 0) lg[c] = ab * d + send[c];
    }
    __syncthreads();
    float x = (lane < NCLS) ? lg[lane] : -3.0e38f;
    float m = wave_max(x);
    float ex = (lane < NCLS) ? expf(x - m) : 0.0f;
    float s = wave_sum(ex);
    if (lane < NCLS) out[b * NCLS + lane] = ex / s;
}

// ---------------------------------------------------------------------------
extern "C" void kernel_launch(void* const* d_in, const int* in_sizes, int n_in,
                              void* d_out, int out_size, void* d_ws, size_t ws_size,
                              hipStream_t stream) {
    (void)in_sizes; (void)n_in; (void)out_size; (void)ws_size;
    const int*   iw   = (const int*)d_in[0];
    const int*   ip1  = (const int*)d_in[1];
    const int*   ip2  = (const int*)d_in[2];
    const float* wemb = (const float*)d_in[3];
    const float* pemb = (const float*)d_in[4];
    const float* kf   = (const float*)d_in[5];
    const float* rf   = (const float*)d_in[6];
    const float* gbf  = (const float*)d_in[7];
    const float* kb   = (const float*)d_in[8];
    const float* rb   = (const float*)d_in[9];
    const float* gbb  = (const float*)d_in[10];
    const float* attw = (const float*)d_in[11];
    const float* sena = (const float*)d_in[12];
    const float* senr = (const float*)d_in[13];
    const float* send = (const float*)d_in[14];
    const float* sens = (const float*)d_in[15];
    float* out = (float*)d_out;

    char* p = (char*)d_ws;
    auto take = [&](size_t n) { char* q = p; p += ((n + 255) & ~(size_t)255); return q; };
    // X is dead after xq_gemm; HA aliases it (scan fully overwrites).
    unsigned short* X    = (unsigned short*)take((size_t)BL * DIM * 2);       // 33.5 MB (= HA)
    unsigned short* Ktf  = (unsigned short*)take((size_t)N3 * DIM * 2);
    unsigned short* Ktb  = (unsigned short*)take((size_t)N3 * DIM * 2);
    unsigned short* Btf  = (unsigned short*)take((size_t)N3 * DIM * 2);
    unsigned short* Btb  = (unsigned short*)take((size_t)N3 * DIM * 2);
    unsigned short* XQf  = (unsigned short*)take((size_t)BL * N3 * 2);        // 100.7 MB
    unsigned short* XQb  = (unsigned short*)take((size_t)BL * N3 * 2);        // 100.7 MB
    unsigned short* HB   = (unsigned short*)take((size_t)BL * DIM * 2);       // 33.5 MB
    unsigned short* HC   = (unsigned short*)take((size_t)BL * DIM * 2);       // 33.5 MB
    unsigned short* HD   = (unsigned short*)take((size_t)BL * DIM * 2);       // 33.5 MB
    unsigned short* Hg   = (unsigned short*)take((size_t)2 * HGN * 2);        // 2 MB ping-pong
    float* scores = (float*)take((size_t)BL * 4);
    float* alpha  = (float*)take((size_t)BL * 4);
    float* rbuf   = (float*)take((size_t)BATCH * DIM * 4);
    float* ebuf   = (float*)take((size_t)BATCH * 4);
    float* abuf   = (float*)take((size_t)BATCH * 4);
    unsigned short* HA = X;   // alias

    transpose_kernel<<<dim3(48, 16), 256, 0, stream>>>(kf, Ktf);
    transpose_kernel<<<dim3(48, 16), 256, 0, stream>>>(kb, Ktb);
    transpose_kernel<<<dim3(48, 16), 256, 0, stream>>>(rf, Btf);
    transpose_kernel<<<dim3(48, 16), 256, 0, stream>>>(rb, Btb);
    gather_kernel<<<BL, 64, 0, stream>>>(iw, ip1, ip2, wemb, pemb, X);

    xq_gemm_kernel<<<dim3(128, 8, 8), 256, 0, stream>>>(X, Ktf, Ktb, XQf, XQb);

    {
        const unsigned short* aXQf = XQf; const unsigned short* aXQb = XQb;
        const unsigned short* aBtf = Btf; const unsigned short* aBtb = Btb;
        const float* agbf = gbf; const float* agbb = gbb;
        unsigned short* aHg = Hg;
        unsigned short* aHA = HA; unsigned short* aHB = HB;
        unsigned short* aHC = HC; unsigned short* aHD = HD;
        void* args[] = { &aXQf, &aXQb, &aBtf, &aBtb, &agbf, &agbb,
                         &aHg, &aHA, &aHB, &aHC, &aHD };
        hipLaunchCooperativeKernel((void*)gru_coop_kernel, dim3(256), dim3(512),
                                   args, 0, stream);
    }

    attn_scores_kernel<<<BL, 64, 0, stream>>>(HA, HB, HC, HD, attw, scores);
    softmax_l_kernel<<<BATCH, 64, 0, stream>>>(scores, alpha);
    attn_apply_kernel<<<BATCH, 256, 0, stream>>>(HA, HB, HC, HD, alpha, sena, senr, rbuf, ebuf);
    batch_softmax_kernel<<<1, 64, 0, stream>>>(ebuf, abuf);
    final_out_kernel<<<BATCH, 64, 0, stream>>>(rbuf, abuf, sens, send, out);
}

// Round 7
// 2773.111 us; speedup vs baseline: 3.3031x; 2.0266x over previous
//
#include <hip/hip_runtime.h>
#include <cstddef>
#include <cstdint>

#define BATCH 256
#define SEQL  128
#define BL    (BATCH * SEQL)   // 32768 rows of x
#define DIM   512              // 448 + 32 + 32 (== UNITS)
#define N3    1536             // 3 * UNITS
#define NCLS  53
#define HGN   (4 * 256 * 512)  // one H ping-pong buffer (elems)

typedef float f32x4 __attribute__((ext_vector_type(4)));
typedef short s16x8 __attribute__((ext_vector_type(8)));
typedef short s16x4 __attribute__((ext_vector_type(4)));

__device__ __forceinline__ float bf2f(unsigned short u) {
    union { unsigned int i; float f; } v; v.i = ((unsigned int)u) << 16; return v.f;
}
__device__ __forceinline__ unsigned short f2bf(float f) {
    union { float f; unsigned int i; } v; v.f = f;
    unsigned int x = v.i;
    return (unsigned short)((x + 0x7fffu + ((x >> 16) & 1u)) >> 16);  // RNE
}
__device__ __forceinline__ float wave_sum(float v) {
    #pragma unroll
    for (int m = 32; m > 0; m >>= 1) v += __shfl_xor(v, m);
    return v;
}
__device__ __forceinline__ float wave_max(float v) {
    #pragma unroll
    for (int m = 32; m > 0; m >>= 1) v = fmaxf(v, __shfl_xor(v, m));
    return v;
}
__device__ __forceinline__ float sigmoidf(float x) { return 1.0f / (1.0f + expf(-x)); }

// ---------------------------------------------------------------------------
// Zero the 8 group-barrier counters (padded to 128 B apart).
__global__ __launch_bounds__(64) void zero_bar_kernel(int* bar) {
    bar[threadIdx.x * 32] = 0;   // covers grp 0..7 (and padding slots)
}

// ---------------------------------------------------------------------------
// Transpose + bf16-cast a [512,1536] fp32 weight into Wt[1536,512] bf16.
__global__ __launch_bounds__(256) void transpose_kernel(const float* __restrict__ W,
                                                        unsigned short* __restrict__ Wt) {
    __shared__ float tile[32][33];
    int tx = threadIdx.x & 31, ty = threadIdx.x >> 5;  // ty: 0..7
    int n0 = blockIdx.x * 32, k0 = blockIdx.y * 32;    // grid (48,16)
    #pragma unroll
    for (int r = 0; r < 4; ++r) {
        int kl = ty + r * 8;
        tile[kl][tx] = W[(size_t)(k0 + kl) * N3 + n0 + tx];
    }
    __syncthreads();
    #pragma unroll
    for (int r = 0; r < 4; ++r) {
        int nl = ty + r * 8;
        Wt[(size_t)(n0 + nl) * DIM + k0 + tx] = f2bf(tile[tx][nl]);
    }
}

// ---------------------------------------------------------------------------
// Gather word/pos embeddings -> X [32768, 512] bf16 (concat 448+32+32).
__global__ __launch_bounds__(64) void gather_kernel(const int* __restrict__ iw,
                                                    const int* __restrict__ ip1,
                                                    const int* __restrict__ ip2,
                                                    const float* __restrict__ wemb,
                                                    const float* __restrict__ pemb,
                                                    unsigned short* __restrict__ X) {
    int row = blockIdx.x;           // b*128 + l
    int tid = threadIdx.x;          // 64 threads x 8 elems
    int w = iw[row], p1 = ip1[row], p2 = ip2[row];
    int e0 = tid * 8;
    s16x8 o;
    #pragma unroll
    for (int j = 0; j < 8; ++j) {
        int e = e0 + j;
        float f;
        if (e < 448)      f = wemb[(size_t)w * 448 + e];
        else if (e < 480) f = pemb[p1 * 32 + (e - 448)];
        else              f = pemb[p2 * 32 + (e - 480)];
        o[j] = (short)f2bf(f);
    }
    *(s16x8*)(X + (size_t)row * DIM + e0) = o;
}

// ---------------------------------------------------------------------------
// XQ[dir] = X @ kernel[dir], FRAGMENT-MAJOR layout (validated rounds 5/6):
// element (b, l, n = g*512+u) at
//   ((l*8 + (b>>5))*8 + (u>>6))*6144 + ((g*4 + ((u>>4)&3))*2 + ((b>>4)&1))*256
//   + ((u&15) | (((b>>2)&3)<<4))*4 + (b&3)
__global__ __launch_bounds__(256, 4) void xq_gemm_kernel(const unsigned short* __restrict__ X,
                                                         const unsigned short* __restrict__ Ktf,
                                                         const unsigned short* __restrict__ Ktb,
                                                         unsigned short* __restrict__ XQf,
                                                         unsigned short* __restrict__ XQb) {
    int dir = blockIdx.z & 1;
    int ns  = blockIdx.z >> 1;           // 0..3 -> u0 = ns*128
    const unsigned short* Kt = dir ? Ktb : Ktf;
    unsigned short* XQ = dir ? XQb : XQf;
    int l    = blockIdx.x;               // 0..127
    int bblk = blockIdx.y;               // 0..7
    int b0 = bblk * 32;
    int u0 = ns * 128;

    __shared__ alignas(16) unsigned short As[32 * 512];   // 32 KB
    int tid = threadIdx.x;
    #pragma unroll
    for (int it = 0; it < 8; ++it) {
        int lin = (it * 256 + tid) * 16;      // byte offset (pre-swizzle)
        int row = lin >> 10;                  // 0..31
        int off = lin & 1023;
        const char* src = (const char*)X + ((((size_t)(b0 + row)) * 128 + l) << 10) + off;
        *(s16x8*)((char*)As + (lin ^ ((row & 7) << 4))) = *(const s16x8*)src;
    }
    __syncthreads();

    int lane = tid & 63, wv = tid >> 6;
    int mi = wv >> 1, wc = wv & 1;
    int lr = lane & 15, lg = lane >> 4;

    f32x4 acc[3][4];
    #pragma unroll
    for (int g = 0; g < 3; ++g)
        #pragma unroll
        for (int ni = 0; ni < 4; ++ni) acc[g][ni] = (f32x4){0.f, 0.f, 0.f, 0.f};

    int ar = mi * 16 + lr;
    #pragma unroll 4
    for (int kk = 0; kk < 16; ++kk) {
        s16x8 a = *(const s16x8*)((const char*)As +
                    (((ar << 10) + (kk << 6) + (lg << 4)) ^ ((ar & 7) << 4)));
        #pragma unroll
        for (int g = 0; g < 3; ++g)
            #pragma unroll
            for (int ni = 0; ni < 4; ++ni) {
                int brow = g * 512 + u0 + wc * 64 + ni * 16 + lr;
                s16x8 b = *(const s16x8*)(Kt + ((size_t)brow << 9) + (kk << 5) + (lg << 3));
                acc[g][ni] = __builtin_amdgcn_mfma_f32_16x16x32_bf16(a, b, acc[g][ni], 0, 0, 0);
            }
    }

    int w_t = ns * 2 + wc;
    #pragma unroll
    for (int g = 0; g < 3; ++g)
        #pragma unroll
        for (int ni = 0; ni < 4; ++ni) {
            size_t base = (((size_t)l * 8 + bblk) * 8 + w_t) * 6144
                        + (size_t)((g * 4 + ni) * 2 + mi) * 256;
            s16x4 o;
            #pragma unroll
            for (int reg = 0; reg < 4; ++reg) o[reg] = (short)f2bf(acc[g][ni][reg]);
            *(s16x4*)(XQ + base + lane * 4) = o;
        }
}

// ---------------------------------------------------------------------------
// Lightweight 32-WG group barrier (monotonic counter, one per group,
// counters 128 B apart). Same fence mechanics as cg::grid_group::sync
// (validated r6) but single-phase and 32-way instead of 256-way.
__device__ __forceinline__ void group_barrier(int* cnt, int target) {
    __syncthreads();
    if (threadIdx.x == 0) {
        __hip_atomic_fetch_add(cnt, 1, __ATOMIC_RELEASE, __HIP_MEMORY_SCOPE_AGENT);
        while (__hip_atomic_load(cnt, __ATOMIC_RELAXED, __HIP_MEMORY_SCOPE_AGENT) < target)
            __builtin_amdgcn_s_sleep(1);
        __hip_atomic_fetch_add(cnt, 0, __ATOMIC_ACQUIRE, __HIP_MEMORY_SCOPE_AGENT);
    }
    __syncthreads();
}

// ---------------------------------------------------------------------------
// Persistent GRU scan: 256 WGs x 512 thr. WG decode: grp = wg&7 (run=grp&3,
// rowh=grp>>2), uslc = wg>>3. Weight slice (48 KB) LDS-resident; fp32 master
// state in registers; H exchanged via 1 MB global ping-pong; one group
// barrier (32 WGs, same XCD under round-robin dispatch) per step.
// Runs: 0=GRU_f(x_f)->HA slot t; 1=GRU_f(x_b)->HB slot t;
//       2=GRU_b(x_b)->HC slot 127-t; 3=GRU_b(x_f)->HD slot 127-t.
__global__ __launch_bounds__(512, 2) void gru_coop2_kernel(
    const unsigned short* __restrict__ XQf, const unsigned short* __restrict__ XQb,
    const unsigned short* __restrict__ Btf, const unsigned short* __restrict__ Btb,
    const float* __restrict__ gbf, const float* __restrict__ gbb,
    unsigned short* __restrict__ Hg, int* __restrict__ bar,
    unsigned short* __restrict__ HA, unsigned short* __restrict__ HB,
    unsigned short* __restrict__ HC, unsigned short* __restrict__ HD) {
    int wg = blockIdx.x;                 // 0..255
    int grp  = wg & 7;
    int run  = grp & 3;
    int rowh = grp >> 2;                 // 0..1
    int uslc = wg >> 3;                  // 0..31
    int* cnt = bar + grp * 32;           // 128 B apart
    const unsigned short* Bt = (run < 2) ? Btf : Btb;
    const unsigned short* XQ = (run < 2) ? XQf : XQb;
    const float* gb = (run < 2) ? gbf : gbb;
    unsigned short* Hout = (run == 0) ? HA : (run == 1) ? HB : (run == 2) ? HC : HD;
    bool revx = (run == 1 || run == 2);
    bool revo = (run >= 2);

    int tid = threadIdx.x;
    int lane = tid & 63, wv = tid >> 6;  // wv 0..7 -> m-tile rowh*128 + wv*16
    int lr = lane & 15, lg = lane >> 4;

    // ---- weight slice -> LDS (48 rows x 512, XOR-swizzled) ----
    __shared__ alignas(16) unsigned short Ws[48 * 512];   // 48 KB
    #pragma unroll
    for (int it = 0; it < 6; ++it) {
        int lin = (it * 512 + tid) * 16;   // byte
        int wrow = lin >> 10;              // 0..47 = g*16 + i
        int off = lin & 1023;
        int g = wrow >> 4, i = wrow & 15;
        const char* src = (const char*)Bt + (((size_t)(g * 512 + uslc * 16 + i)) << 10) + off;
        *(s16x8*)((char*)Ws + (lin ^ ((wrow & 7) << 4))) = *(const s16x8*)src;
    }

    int u_col = uslc * 16 + lr;
    float bZv  = gb[u_col] + gb[N3 + u_col];
    float bRv  = gb[512 + u_col] + gb[N3 + 512 + u_col];
    float bIHv = gb[1024 + u_col];
    float bRHv = gb[N3 + 1024 + u_col];

    int mrow0 = rowh * 128 + wv * 16;    // m-tile base row (batch index)
    int arow  = mrow0 + lr;              // A-fragment row
    int bblk = rowh * 4 + (wv >> 1);
    int mi = wv & 1;
    int w_t = uslc >> 2, ni_t = uslc & 3;

    // zero initial state (own elements of Hg buffer 0) + register master
    f32x4 hm = (f32x4){0.f, 0.f, 0.f, 0.f};
    #pragma unroll
    for (int reg = 0; reg < 4; ++reg) {
        int row = mrow0 + lg * 4 + reg;
        Hg[((size_t)(run * 256 + row) << 9) + u_col] = 0;
    }
    int target = 32;
    group_barrier(cnt, target); target += 32;

    for (int t = 0; t < SEQL; ++t) {
        const unsigned short* cur = Hg + (size_t)(t & 1) * HGN;
        unsigned short* nxt = Hg + (size_t)((t + 1) & 1) * HGN;
        int tx = revx ? (127 - t) : t;
        int th = revo ? (127 - t) : t;

        // x-projection fragments (3 coalesced 8-B loads)
        const unsigned short* xqb = XQ + (((size_t)tx * 8 + bblk) * 8 + w_t) * 6144
                                       + (size_t)lane * 4;
        s16x4 xqz = *(const s16x4*)(xqb + ((0 * 4 + ni_t) * 2 + mi) * 256);
        s16x4 xqr = *(const s16x4*)(xqb + ((1 * 4 + ni_t) * 2 + mi) * 256);
        s16x4 xqh = *(const s16x4*)(xqb + ((2 * 4 + ni_t) * 2 + mi) * 256);

        const unsigned short* ap = cur + ((size_t)(run * 256 + arow) << 9) + (lg << 3);

        f32x4 aZ = (f32x4){0.f, 0.f, 0.f, 0.f};
        f32x4 aR = (f32x4){0.f, 0.f, 0.f, 0.f};
        f32x4 aH = (f32x4){0.f, 0.f, 0.f, 0.f};
        const char* wsb = (const char*)Ws;
        #pragma unroll 8
        for (int kk = 0; kk < 16; ++kk) {
            s16x8 a = *(const s16x8*)(ap + (kk << 5));
            int sw = (lr & 7) << 4;
            s16x8 bz = *(const s16x8*)(wsb + ((((0 * 16 + lr) << 10) + (kk << 6) + (lg << 4)) ^ sw));
            s16x8 br = *(const s16x8*)(wsb + ((((1 * 16 + lr) << 10) + (kk << 6) + (lg << 4)) ^ sw));
            s16x8 bh = *(const s16x8*)(wsb + ((((2 * 16 + lr) << 10) + (kk << 6) + (lg << 4)) ^ sw));
            aZ = __builtin_amdgcn_mfma_f32_16x16x32_bf16(a, bz, aZ, 0, 0, 0);
            aR = __builtin_amdgcn_mfma_f32_16x16x32_bf16(a, br, aR, 0, 0, 0);
            aH = __builtin_amdgcn_mfma_f32_16x16x32_bf16(a, bh, aH, 0, 0, 0);
        }

        #pragma unroll
        for (int reg = 0; reg < 4; ++reg) {
            int row = mrow0 + lg * 4 + reg;
            float z  = sigmoidf(bf2f((unsigned short)xqz[reg]) + bZv + aZ[reg]);
            float rg = sigmoidf(bf2f((unsigned short)xqr[reg]) + bRv + aR[reg]);
            float hh = tanhf(bf2f((unsigned short)xqh[reg]) + bIHv + rg * (aH[reg] + bRHv));
            float hn = z * hm[reg] + (1.0f - z) * hh;
            hm[reg] = hn;
            unsigned short hb = f2bf(hn);
            nxt[((size_t)(run * 256 + row) << 9) + u_col] = hb;
            Hout[(((size_t)row * SEQL) + th) * DIM + u_col] = hb;
        }
        if (t < SEQL - 1) { group_barrier(cnt, target); target += 32; }
    }
}

// ---------------------------------------------------------------------------
// scores[b,l] = sum_u tanh(h[b,l,u]) * attw[u],  h = HA+HB+HC+HD
__global__ __launch_bounds__(64) void attn_scores_kernel(const unsigned short* __restrict__ HA,
                                                         const unsigned short* __restrict__ HB,
                                                         const unsigned short* __restrict__ HC,
                                                         const unsigned short* __restrict__ HD,
                                                         const float* __restrict__ attw,
                                                         float* __restrict__ scores) {
    int bl = blockIdx.x;   // grid 32768
    int lane = threadIdx.x;
    size_t base = (size_t)bl * DIM + lane * 8;
    s16x8 h1 = *(const s16x8*)(HA + base);
    s16x8 h2 = *(const s16x8*)(HB + base);
    s16x8 h3 = *(const s16x8*)(HC + base);
    s16x8 h4 = *(const s16x8*)(HD + base);
    float s = 0.0f;
    #pragma unroll
    for (int j = 0; j < 8; ++j) {
        float hv = bf2f((unsigned short)h1[j]) + bf2f((unsigned short)h2[j])
                 + bf2f((unsigned short)h3[j]) + bf2f((unsigned short)h4[j]);
        s += tanhf(hv) * attw[lane * 8 + j];
    }
    s = wave_sum(s);
    if (lane == 0) scores[bl] = s;
}

// alpha[b,:] = softmax over L=128
__global__ __launch_bounds__(64) void softmax_l_kernel(const float* __restrict__ scores,
                                                       float* __restrict__ alpha) {
    int b = blockIdx.x, lane = threadIdx.x;
    float s0 = scores[b * SEQL + lane];
    float s1 = scores[b * SEQL + 64 + lane];
    float m = wave_max(fmaxf(s0, s1));
    float e0 = expf(s0 - m), e1 = expf(s1 - m);
    float sum = wave_sum(e0 + e1);
    alpha[b * SEQL + lane] = e0 / sum;
    alpha[b * SEQL + 64 + lane] = e1 / sum;
}

// w_att_r[b,u] = sum_l alpha*h ; r = tanh(w); e[b] = sum_u r*sen_a*sen_r
__global__ __launch_bounds__(512) void attn_apply_kernel(const unsigned short* __restrict__ HA,
                                                         const unsigned short* __restrict__ HB,
                                                         const unsigned short* __restrict__ HC,
                                                         const unsigned short* __restrict__ HD,
                                                         const float* __restrict__ alpha,
                                                         const float* __restrict__ sena,
                                                         const float* __restrict__ senr,
                                                         float* __restrict__ rbuf,
                                                         float* __restrict__ ebuf) {
    int b = blockIdx.x, tid = threadIdx.x;   // tid = u
    __shared__ float al[SEQL];
    __shared__ float red[8];
    if (tid < SEQL) al[tid] = alpha[b * SEQL + tid];
    __syncthreads();
    float w0 = 0.0f;
    #pragma unroll 2
    for (int l = 0; l < SEQL; ++l) {
        size_t base = ((size_t)b * SEQL + l) * DIM + tid;
        w0 += al[l] * (bf2f(HA[base]) + bf2f(HB[base]) + bf2f(HC[base]) + bf2f(HD[base]));
    }
    float r0 = tanhf(w0);
    rbuf[(size_t)b * DIM + tid] = r0;
    float pv = r0 * sena[tid] * senr[tid];
    pv = wave_sum(pv);
    if ((tid & 63) == 0) red[tid >> 6] = pv;
    __syncthreads();
    if (tid == 0) {
        float s = 0.0f;
        #pragma unroll
        for (int i = 0; i < 8; ++i) s += red[i];
        ebuf[b] = s;
    }
}

// a = softmax over batch (256)
__global__ __launch_bounds__(64) void batch_softmax_kernel(const float* __restrict__ ebuf,
                                                           float* __restrict__ abuf) {
    int lane = threadIdx.x;
    float v0 = ebuf[lane], v1 = ebuf[64 + lane], v2 = ebuf[128 + lane], v3 = ebuf[192 + lane];
    float m = wave_max(fmaxf(fmaxf(v0, v1), fmaxf(v2, v3)));
    float e0 = expf(v0 - m), e1 = expf(v1 - m), e2 = expf(v2 - m), e3 = expf(v3 - m);
    float s = wave_sum(e0 + e1 + e2 + e3);
    abuf[lane] = e0 / s; abuf[64 + lane] = e1 / s;
    abuf[128 + lane] = e2 / s; abuf[192 + lane] = e3 / s;
}

// logits[b,c] = a[b]*(r[b]·sen_s[c]) + sen_d[c]; out = softmax over c
__global__ __launch_bounds__(64) void final_out_kernel(const float* __restrict__ rbuf,
                                                       const float* __restrict__ abuf,
                                                       const float* __restrict__ sens,
                                                       const float* __restrict__ send,
                                                       float* __restrict__ out) {
    int b = blockIdx.x, lane = threadIdx.x;
    __shared__ float lg[NCLS];
    float ab = abuf[b];
    float rv[8];
    #pragma unroll
    for (int j = 0; j < 8; ++j) rv[j] = rbuf[(size_t)b * DIM + j * 64 + lane];
    for (int c = 0; c < NCLS; ++c) {
        float d = 0.0f;
        #pragma unroll
        for (int j = 0; j < 8; ++j) d += rv[j] * sens[(size_t)c * DIM + j * 64 + lane];
        d = wave_sum(d);
        if (lane == 0) lg[c] = ab * d + send[c];
    }
    __syncthreads();
    float x = (lane < NCLS) ? lg[lane] : -3.0e38f;
    float m = wave_max(x);
    float ex = (lane < NCLS) ? expf(x - m) : 0.0f;
    float s = wave_sum(ex);
    if (lane < NCLS) out[b * NCLS + lane] = ex / s;
}

// ---------------------------------------------------------------------------
extern "C" void kernel_launch(void* const* d_in, const int* in_sizes, int n_in,
                              void* d_out, int out_size, void* d_ws, size_t ws_size,
                              hipStream_t stream) {
    (void)in_sizes; (void)n_in; (void)out_size; (void)ws_size;
    const int*   iw   = (const int*)d_in[0];
    const int*   ip1  = (const int*)d_in[1];
    const int*   ip2  = (const int*)d_in[2];
    const float* wemb = (const float*)d_in[3];
    const float* pemb = (const float*)d_in[4];
    const float* kf   = (const float*)d_in[5];
    const float* rf   = (const float*)d_in[6];
    const float* gbf  = (const float*)d_in[7];
    const float* kb   = (const float*)d_in[8];
    const float* rb   = (const float*)d_in[9];
    const float* gbb  = (const float*)d_in[10];
    const float* attw = (const float*)d_in[11];
    const float* sena = (const float*)d_in[12];
    const float* senr = (const float*)d_in[13];
    const float* send = (const float*)d_in[14];
    const float* sens = (const float*)d_in[15];
    float* out = (float*)d_out;

    char* p = (char*)d_ws;
    auto take = [&](size_t n) { char* q = p; p += ((n + 255) & ~(size_t)255); return q; };
    // X is dead after xq_gemm; HA aliases it (scan fully overwrites).
    unsigned short* X    = (unsigned short*)take((size_t)BL * DIM * 2);       // 33.5 MB (= HA)
    unsigned short* Ktf  = (unsigned short*)take((size_t)N3 * DIM * 2);
    unsigned short* Ktb  = (unsigned short*)take((size_t)N3 * DIM * 2);
    unsigned short* Btf  = (unsigned short*)take((size_t)N3 * DIM * 2);
    unsigned short* Btb  = (unsigned short*)take((size_t)N3 * DIM * 2);
    unsigned short* XQf  = (unsigned short*)take((size_t)BL * N3 * 2);        // 100.7 MB
    unsigned short* XQb  = (unsigned short*)take((size_t)BL * N3 * 2);        // 100.7 MB
    unsigned short* HB   = (unsigned short*)take((size_t)BL * DIM * 2);       // 33.5 MB
    unsigned short* HC   = (unsigned short*)take((size_t)BL * DIM * 2);       // 33.5 MB
    unsigned short* HD   = (unsigned short*)take((size_t)BL * DIM * 2);       // 33.5 MB
    unsigned short* Hg   = (unsigned short*)take((size_t)2 * HGN * 2);        // 2 MB ping-pong
    int*            bar  = (int*)take((size_t)64 * 32 * 4);                   // padded counters
    float* scores = (float*)take((size_t)BL * 4);
    float* alpha  = (float*)take((size_t)BL * 4);
    float* rbuf   = (float*)take((size_t)BATCH * DIM * 4);
    float* ebuf   = (float*)take((size_t)BATCH * 4);
    float* abuf   = (float*)take((size_t)BATCH * 4);
    unsigned short* HA = X;   // alias

    zero_bar_kernel<<<1, 64, 0, stream>>>(bar);
    transpose_kernel<<<dim3(48, 16), 256, 0, stream>>>(kf, Ktf);
    transpose_kernel<<<dim3(48, 16), 256, 0, stream>>>(kb, Ktb);
    transpose_kernel<<<dim3(48, 16), 256, 0, stream>>>(rf, Btf);
    transpose_kernel<<<dim3(48, 16), 256, 0, stream>>>(rb, Btb);
    gather_kernel<<<BL, 64, 0, stream>>>(iw, ip1, ip2, wemb, pemb, X);

    xq_gemm_kernel<<<dim3(128, 8, 8), 256, 0, stream>>>(X, Ktf, Ktb, XQf, XQb);

    {
        const unsigned short* aXQf = XQf; const unsigned short* aXQb = XQb;
        const unsigned short* aBtf = Btf; const unsigned short* aBtb = Btb;
        const float* agbf = gbf; const float* agbb = gbb;
        unsigned short* aHg = Hg; int* abar = bar;
        unsigned short* aHA = HA; unsigned short* aHB = HB;
        unsigned short* aHC = HC; unsigned short* aHD = HD;
        void* args[] = { &aXQf, &aXQb, &aBtf, &aBtb, &agbf, &agbb,
                         &aHg, &abar, &aHA, &aHB, &aHC, &aHD };
        hipLaunchCooperativeKernel((void*)gru_coop2_kernel, dim3(256), dim3(512),
                                   args, 0, stream);
    }

    attn_scores_kernel<<<BL, 64, 0, stream>>>(HA, HB, HC, HD, attw, scores);
    softmax_l_kernel<<<BATCH, 64, 0, stream>>>(scores, alpha);
    attn_apply_kernel<<<BATCH, 512, 0, stream>>>(HA, HB, HC, HD, alpha, sena, senr, rbuf, ebuf);
    batch_softmax_kernel<<<1, 64, 0, stream>>>(ebuf, abuf);
    final_out_kernel<<<BATCH, 64, 0, stream>>>(rbuf, abuf, sens, send, out);
}